// Round 2
// 441.239 us; speedup vs baseline: 1.0046x; 1.0046x over previous
//
#include <hip/hip_runtime.h>

// argmin_c ||x-c|| == argmin_c (||c||^2 - 2 x.c). Cross-term via 3 f16 MFMA
// GEMMs (exact hi/lo split of fp32, lo*lo dropped ~2^-22 rel).
// Round 8 (resubmit; round-1 bench was an infra failure, no counters): 
// latency-shaped register pipeline. Round-7 counters: MfmaUtil 51%,
// VGPR=104(+64 acc) -> the compiler collapsed the ping-pong (a true 2-set
// pipeline needs ~200 regs live). Cause: comp was i-outer/j-inner, so B[j]
// regs stay live across the whole phase and B(kt+1) can't be issued early.
// FETCH=424MB ~= A-once + 3x B re-reads: A is XCD-L2-resident (~200cyc), B
// thrashes L2 and comes from L3 (~450cyc). Fix: j-outer/i-inner comp so B[j]
// dies after its 12 MFMAs, B(kt+1) issued a full comp phase (~470cyc) ahead,
// A(kt+1) issued mid-phase (~230cyc) ahead. Term order per acc element
// (hh,hl,lh per kt) unchanged -> bit-identical scores.
// Also: csq fused into fragpack as extra wave-tasks (one fewer launch).
typedef __fp16 f16x2 __attribute__((ext_vector_type(2)));
typedef __fp16 f16x8 __attribute__((ext_vector_type(8)));
typedef float f32x4 __attribute__((ext_vector_type(4)));

constexpr int MM = 32768;   // B*T tokens
constexpr int NN = 2048;    // clusters
constexpr int KK = 768;     // dim
constexpr int BM = 128;     // tokens per block
constexpr int BN = 128;     // clusters per block
constexpr int NKT = KK / 32;          // 24 k-tiles
constexpr int NA_UNITS = (MM / 16) * NKT;   // 49152 A (mt,kt) wave-tasks
constexpr int NB_UNITS = (NN / 16) * NKT;   //  3072 B (nt,kt) wave-tasks

// Workspace layout (bytes). Apack: [mt][kt][part] 1KB units; Bpack same.
constexpr size_t WS_APACK = 0;
constexpr size_t WS_BPACK = WS_APACK + (size_t)MM * KK * 4;  // 100663296
constexpr size_t WS_CSQ   = WS_BPACK + (size_t)NN * KK * 4;  // 106954752
constexpr size_t WS_SLOT  = WS_CSQ + (size_t)NN * 4;         // 106962944
constexpr size_t WS_NEED  = WS_SLOT + (size_t)MM * 16 * 8;   // 111157248

__device__ __forceinline__ unsigned bc(f16x2 h) {
    return __builtin_bit_cast(unsigned, h);
}

// ---------------- fast path ----------------

// One wave packs one (tile16, ktile32, {hi,lo}) pair: reads 16 rows x 128B of
// fp32, writes two contiguous 1KB units in fragment order
// (byte off = (quad*16 + ln15)*16 holds elements m=ln15, k=quad*8..+7).
// Tail tasks (task >= NA+NB) compute csq: one wave per cluster row.
__global__ __launch_bounds__(256)
void fragpack_kernel(const float* __restrict__ A, const float* __restrict__ Bc,
                     uint4* __restrict__ Ap, uint4* __restrict__ Bp,
                     float* __restrict__ csq) {
    const int task = blockIdx.x * 4 + (threadIdx.x >> 6);
    const int lane = threadIdx.x & 63;

    if (task >= NA_UNITS + NB_UNITS) {          // csq tail: wave-uniform branch
        const int cl = task - (NA_UNITS + NB_UNITS);
        const float4* row = reinterpret_cast<const float4*>(Bc + (size_t)cl * KK);
        float s = 0.f;
#pragma unroll
        for (int w = 0; w < KK / (4 * 64); ++w) {
            float4 v = row[w * 64 + lane];
            s = fmaf(v.x, v.x, s); s = fmaf(v.y, v.y, s);
            s = fmaf(v.z, v.z, s); s = fmaf(v.w, v.w, s);
        }
#pragma unroll
        for (int off = 32; off > 0; off >>= 1) s += __shfl_xor(s, off, 64);
        if (lane == 0) csq[cl] = s;
        return;
    }

    const int ln15 = lane & 15;
    const int quad = lane >> 4;

    const bool isB = task >= NA_UNITS;
    const int t = isB ? task - NA_UNITS : task;
    const int tile = t / NKT, kt = t % NKT;
    const float* src = (isB ? Bc : A) + (size_t)(tile * 16 + ln15) * KK + kt * 32 + quad * 8;
    uint4* dst = (isB ? Bp : Ap) + (size_t)t * 128 + lane;   // 2 units = 128 uint4

    const float4 v0 = *(const float4*)(src);
    const float4 v1 = *(const float4*)(src + 4);
    f16x2 h0 = __builtin_amdgcn_cvt_pkrtz(v0.x, v0.y);
    f16x2 h1 = __builtin_amdgcn_cvt_pkrtz(v0.z, v0.w);
    f16x2 h2 = __builtin_amdgcn_cvt_pkrtz(v1.x, v1.y);
    f16x2 h3 = __builtin_amdgcn_cvt_pkrtz(v1.z, v1.w);
    f16x2 l0 = __builtin_amdgcn_cvt_pkrtz(v0.x-(float)h0[0], v0.y-(float)h0[1]);
    f16x2 l1 = __builtin_amdgcn_cvt_pkrtz(v0.z-(float)h1[0], v0.w-(float)h1[1]);
    f16x2 l2 = __builtin_amdgcn_cvt_pkrtz(v1.x-(float)h2[0], v1.y-(float)h2[1]);
    f16x2 l3 = __builtin_amdgcn_cvt_pkrtz(v1.z-(float)h3[0], v1.w-(float)h3[1]);
    uint4 hv = {bc(h0), bc(h1), bc(h2), bc(h3)};
    uint4 lv = {bc(l0), bc(l1), bc(l2), bc(l3)};
    dst[0]  = hv;
    dst[64] = lv;
}

__global__ __launch_bounds__(64)
void csq_kernel(const float* __restrict__ cc, float* __restrict__ csq) {
    const int cl = blockIdx.x;
    const int lane = threadIdx.x;
    const float4* row = reinterpret_cast<const float4*>(cc + (size_t)cl * KK);
    float s = 0.f;
#pragma unroll
    for (int w = 0; w < KK / (4 * 64); ++w) {
        float4 v = row[w * 64 + lane];
        s = fmaf(v.x, v.x, s); s = fmaf(v.y, v.y, s);
        s = fmaf(v.z, v.z, s); s = fmaf(v.w, v.w, s);
    }
#pragma unroll
    for (int off = 32; off > 0; off >>= 1) s += __shfl_xor(s, off, 64);
    if (lane == 0) csq[cl] = s;
}

#define MF(a, b, c) __builtin_amdgcn_mfma_f32_16x16x32_f16( \
    __builtin_bit_cast(f16x8, a), __builtin_bit_cast(f16x8, b), c, 0, 0, 0)

// One j-phase of compute: 12 MFMAs consuming Bh_[j]/Bl_[j] (then dead) and
// reusing all Ah_/Al_. j is a literal at every expansion -> acc index static.
#define COMP_J(Ah_, Al_, Bh_, Bl_, j) \
    _Pragma("unroll") \
    for (int i = 0; i < 4; ++i) { \
        acc[i][j] = MF(Ah_[i], Bh_[j], acc[i][j]); \
        acc[i][j] = MF(Ah_[i], Bl_[j], acc[i][j]); \
        acc[i][j] = MF(Al_[i], Bh_[j], acc[i][j]); \
    }

#define LOAD_B(Bh_, Bl_, kt_) { const int o_ = (kt_) * 128; \
    _Pragma("unroll") \
    for (int j = 0; j < 4; ++j) { Bh_[j] = b_ptr[j][o_]; Bl_[j] = b_ptr[j][o_ + 64]; } }

#define LOAD_A(Ah_, Al_, kt_) { const int o_ = (kt_) * 128; \
    _Pragma("unroll") \
    for (int i = 0; i < 4; ++i) { Ah_[i] = a_ptr[i][o_]; Al_[i] = a_ptr[i][o_ + 64]; } }

__global__ __launch_bounds__(256, 2)
void gemm_pack_kernel(const uint4* __restrict__ Ap, const uint4* __restrict__ Bp,
                      const float* __restrict__ csq, uint2* __restrict__ slots) {
    // XCD-aware swizzle: xcd = b&7 (round-robin dispatch); the 16 gx-blocks
    // sharing one A tile (same gy) get ids base+8j -> same XCD -> A tile is
    // that XCD's-L2-resident after first touch.
    const int b   = blockIdx.x;
    const int xcd = b & 7;
    const int s   = b >> 3;            // 0..511 sequence within XCD
    const int gx  = s & 15;            // n-block
    const int gy  = xcd + ((s >> 4) << 3);   // m-block 0..255

    const int tid  = threadIdx.x;
    const int lane = tid & 63;
    const int ln15 = lane & 15;
    const int quad = lane >> 4;
    const int wave = tid >> 6;
    const int wm = wave >> 1, wn = wave & 1;
    const int tbase = gy * BM;
    const int cb    = gx * BN;

    // Fragment unit pointers (uint4 granularity; unit = 64 uint4; kt step = 128).
    const uint4* a_ptr[4];
    const uint4* b_ptr[4];
#pragma unroll
    for (int i = 0; i < 4; ++i) {
        a_ptr[i] = Ap + (size_t)(gy * 8 + wm * 4 + i) * NKT * 128 + lane;
        b_ptr[i] = Bp + (size_t)(gx * 8 + wn * 4 + i) * NKT * 128 + lane;
    }

    f32x4 acc[4][4];
#pragma unroll
    for (int i = 0; i < 4; ++i)
#pragma unroll
        for (int j = 0; j < 4; ++j) { f32x4 z = {0.f,0.f,0.f,0.f}; acc[i][j] = z; }

    uint4 Ah0[4], Al0[4], Bh0[4], Bl0[4];
    uint4 Ah1[4], Al1[4], Bh1[4], Bl1[4];

    // Pipeline (no barriers): B prefetched a full comp phase ahead (~470cyc,
    // covers L3), A prefetched half a phase ahead (~230cyc, covers XCD-L2).
    LOAD_B(Bh0, Bl0, 0)
    LOAD_A(Ah0, Al0, 0)
#pragma unroll 1
    for (int kt = 0; kt < NKT; kt += 2) {
        LOAD_B(Bh1, Bl1, kt + 1)
        COMP_J(Ah0, Al0, Bh0, Bl0, 0)
        COMP_J(Ah0, Al0, Bh0, Bl0, 1)
        LOAD_A(Ah1, Al1, kt + 1)
        COMP_J(Ah0, Al0, Bh0, Bl0, 2)
        COMP_J(Ah0, Al0, Bh0, Bl0, 3)
        if (kt + 2 < NKT) LOAD_B(Bh0, Bl0, kt + 2)
        COMP_J(Ah1, Al1, Bh1, Bl1, 0)
        COMP_J(Ah1, Al1, Bh1, Bl1, 1)
        if (kt + 2 < NKT) LOAD_A(Ah0, Al0, kt + 2)
        COMP_J(Ah1, Al1, Bh1, Bl1, 2)
        COMP_J(Ah1, Al1, Bh1, Bl1, 3)
    }

    // Epilogue: score = csq - 2*dot; C/D layout col=lane&15, row=quad*4+reg.
    float csq4[4];
#pragma unroll
    for (int j = 0; j < 4; ++j) csq4[j] = csq[cb + wn * 64 + j * 16 + ln15];

    float bval[16]; int bidx[16];
#pragma unroll
    for (int i = 0; i < 4; ++i)
#pragma unroll
        for (int r = 0; r < 4; ++r) {
            const int rid = i * 4 + r;
            float bv_ = csq4[0] - 2.0f * acc[i][0][r];
            int   bi_ = cb + wn * 64 + ln15;
#pragma unroll
            for (int j = 1; j < 4; ++j) {
                const float s2 = csq4[j] - 2.0f * acc[i][j][r];
                const int   c = cb + wn * 64 + j * 16 + ln15;
                if (s2 < bv_) { bv_ = s2; bi_ = c; }   // ascending c, strict <
            }
            bval[rid] = bv_; bidx[rid] = bi_;
        }
#pragma unroll
    for (int off = 1; off < 16; off <<= 1) {
#pragma unroll
        for (int rid = 0; rid < 16; ++rid) {
            const float ov = __shfl_xor(bval[rid], off, 64);
            const int   oi = __shfl_xor(bidx[rid], off, 64);
            if (ov < bval[rid] || (ov == bval[rid] && oi < bidx[rid])) {
                bval[rid] = ov; bidx[rid] = oi;
            }
        }
    }

    __shared__ float vtab[256];   // [128 rows][2 wn]
    __shared__ int   itab[256];
    if (ln15 == 0) {
#pragma unroll
        for (int i = 0; i < 4; ++i)
#pragma unroll
            for (int r = 0; r < 4; ++r) {
                const int row = wm * 64 + i * 16 + quad * 4 + r;
                vtab[row * 2 + wn] = bval[i * 4 + r];
                itab[row * 2 + wn] = bidx[i * 4 + r];
            }
    }
    __syncthreads();
    if (tid < 128) {
        float v0 = vtab[tid * 2]; int i0 = itab[tid * 2];
        const float v1 = vtab[tid * 2 + 1]; const int i1 = itab[tid * 2 + 1];
        if (v1 < v0 || (v1 == v0 && i1 < i0)) { v0 = v1; i0 = i1; }
        uint2 e; e.x = __float_as_uint(v0); e.y = (unsigned)i0;
        slots[(size_t)(tbase + tid) * 16 + gx] = e;
    }
}

__global__ __launch_bounds__(256)
void slot_reduce_kernel(const uint2* __restrict__ slots, int* __restrict__ out) {
    const int t = blockIdx.x * 256 + threadIdx.x;
    const uint2* s = slots + (size_t)t * 16;
    float bv = __uint_as_float(s[0].x); int bi = (int)s[0].y;
#pragma unroll
    for (int j = 1; j < 16; ++j) {
        const uint2 e = s[j];
        const float v = __uint_as_float(e.x);
        if (v < bv || (v == bv && (int)e.y < bi)) { bv = v; bi = (int)e.y; }
    }
    out[t] = bi;
}

// ---------------- round-3 fallback (proven, used only if ws too small) ------

__global__ __launch_bounds__(256)
void init_ws_kernel(unsigned long long* __restrict__ w) {
    w[blockIdx.x * 256 + threadIdx.x] = 0xFFFFFFFFFFFFFFFFull;
}

__global__ __launch_bounds__(256, 2)
void argmin_mfma_kernel(const float* __restrict__ A, const float* __restrict__ Bc,
                        const float* __restrict__ csq,
                        unsigned long long* __restrict__ ws64) {
    __shared__ unsigned lds[4 * 128 * 20];
    constexpr int AH = 0, AL = 2560, BH = 5120;

    const int tid  = threadIdx.x;
    const int lane = tid & 63;
    const int ln15 = lane & 15;
    const int quad = lane >> 4;
    const int wave = tid >> 6;
    const int wm = wave >> 1, wn = wave & 1;
    const int tbase = blockIdx.x * BM;
    const int cb    = blockIdx.y * BN;

    const int sr  = tid >> 1;
    const int skh = tid & 1;
    const float* gA = A  + (size_t)(tbase + sr) * KK + skh * 16;
    const float* gB = Bc + (size_t)(cb   + sr) * KK + skh * 16;
    const int wword = sr * 20 + skh * 8;

    f32x4 acc[4][4];
#pragma unroll
    for (int i = 0; i < 4; ++i)
#pragma unroll
        for (int j = 0; j < 4; ++j) { f32x4 z = {0.f,0.f,0.f,0.f}; acc[i][j] = z; }

    float4 av[4], bv[4];
#pragma unroll
    for (int p = 0; p < 4; ++p) {
        av[p] = *(const float4*)(gA + p * 4);
        bv[p] = *(const float4*)(gB + p * 4);
    }

    int aw[4], bw[4];
#pragma unroll
    for (int i = 0; i < 4; ++i) {
        aw[i] = AH + (wm * 64 + i * 16 + ln15) * 20 + quad * 4;
        bw[i] = BH + (wn * 64 + i * 16 + ln15) * 20 + quad * 4;
    }

    for (int k0 = 0; k0 < KK; k0 += 32) {
        __syncthreads();
#pragma unroll
        for (int h = 0; h < 2; ++h) {
            float4 v0 = av[2*h], v1 = av[2*h+1];
            f16x2 h00 = __builtin_amdgcn_cvt_pkrtz(v0.x, v0.y);
            f16x2 h01 = __builtin_amdgcn_cvt_pkrtz(v0.z, v0.w);
            f16x2 h10 = __builtin_amdgcn_cvt_pkrtz(v1.x, v1.y);
            f16x2 h11 = __builtin_amdgcn_cvt_pkrtz(v1.z, v1.w);
            f16x2 l00 = __builtin_amdgcn_cvt_pkrtz(v0.x-(float)h00[0], v0.y-(float)h00[1]);
            f16x2 l01 = __builtin_amdgcn_cvt_pkrtz(v0.z-(float)h01[0], v0.w-(float)h01[1]);
            f16x2 l10 = __builtin_amdgcn_cvt_pkrtz(v1.x-(float)h10[0], v1.y-(float)h10[1]);
            f16x2 l11 = __builtin_amdgcn_cvt_pkrtz(v1.z-(float)h11[0], v1.w-(float)h11[1]);
            uint4 hv = {bc(h00), bc(h01), bc(h10), bc(h11)};
            uint4 lv = {bc(l00), bc(l01), bc(l10), bc(l11)};
            *(uint4*)&lds[AH + wword + 4*h] = hv;
            *(uint4*)&lds[AL + wword + 4*h] = lv;

            float4 w0 = bv[2*h], w1 = bv[2*h+1];
            f16x2 g00 = __builtin_amdgcn_cvt_pkrtz(w0.x, w0.y);
            f16x2 g01 = __builtin_amdgcn_cvt_pkrtz(w0.z, w0.w);
            f16x2 g10 = __builtin_amdgcn_cvt_pkrtz(w1.x, w1.y);
            f16x2 g11 = __builtin_amdgcn_cvt_pkrtz(w1.z, w1.w);
            f16x2 m00 = __builtin_amdgcn_cvt_pkrtz(w0.x-(float)g00[0], w0.y-(float)g00[1]);
            f16x2 m01 = __builtin_amdgcn_cvt_pkrtz(w0.z-(float)g01[0], w0.w-(float)g01[1]);
            f16x2 m10 = __builtin_amdgcn_cvt_pkrtz(w1.x-(float)g10[0], w1.y-(float)g10[1]);
            f16x2 m11 = __builtin_amdgcn_cvt_pkrtz(w1.z-(float)g11[0], w1.w-(float)g11[1]);
            uint4 gv = {bc(g00), bc(g01), bc(g10), bc(g11)};
            uint4 mv = {bc(m00), bc(m01), bc(m10), bc(m11)};
            *(uint4*)&lds[BH + wword + 4*h]        = gv;
            *(uint4*)&lds[BH + 2560 + wword + 4*h] = mv;
        }
        __syncthreads();

        const int kn = k0 + 32;
        if (kn < KK) {
#pragma unroll
            for (int p = 0; p < 4; ++p) {
                av[p] = *(const float4*)(gA + kn + p * 4);
                bv[p] = *(const float4*)(gB + kn + p * 4);
            }
        }

        f16x8 a_h[4], a_l[4], b_h[4], b_l[4];
#pragma unroll
        for (int i = 0; i < 4; ++i) {
            a_h[i] = *(const f16x8*)&lds[aw[i]];
            a_l[i] = *(const f16x8*)&lds[aw[i] + 2560];
            b_h[i] = *(const f16x8*)&lds[bw[i]];
            b_l[i] = *(const f16x8*)&lds[bw[i] + 2560];
        }
#pragma unroll
        for (int i = 0; i < 4; ++i)
#pragma unroll
            for (int j = 0; j < 4; ++j) {
                acc[i][j] = __builtin_amdgcn_mfma_f32_16x16x32_f16(a_h[i], b_h[j], acc[i][j], 0, 0, 0);
                acc[i][j] = __builtin_amdgcn_mfma_f32_16x16x32_f16(a_h[i], b_l[j], acc[i][j], 0, 0, 0);
                acc[i][j] = __builtin_amdgcn_mfma_f32_16x16x32_f16(a_l[i], b_h[j], acc[i][j], 0, 0, 0);
            }
    }

    float csq4[4];
#pragma unroll
    for (int j = 0; j < 4; ++j) csq4[j] = csq[cb + wn * 64 + j * 16 + ln15];

    float bval[16]; int bidx[16];
#pragma unroll
    for (int i = 0; i < 4; ++i)
#pragma unroll
        for (int r = 0; r < 4; ++r) {
            const int rid = i * 4 + r;
            float bv_ = csq4[0] - 2.0f * acc[i][0][r];
            int   bi_ = cb + wn * 64 + ln15;
#pragma unroll
            for (int j = 1; j < 4; ++j) {
                const float s = csq4[j] - 2.0f * acc[i][j][r];
                const int   c = cb + wn * 64 + j * 16 + ln15;
                if (s < bv_) { bv_ = s; bi_ = c; }
            }
            bval[rid] = bv_; bidx[rid] = bi_;
        }
#pragma unroll
    for (int off = 1; off < 16; off <<= 1) {
#pragma unroll
        for (int rid = 0; rid < 16; ++rid) {
            const float ov = __shfl_xor(bval[rid], off, 64);
            const int   oi = __shfl_xor(bidx[rid], off, 64);
            if (ov < bval[rid] || (ov == bval[rid] && oi < bidx[rid])) {
                bval[rid] = ov; bidx[rid] = oi;
            }
        }
    }

    __syncthreads();
    float* vtab = (float*)&lds[0];
    int*   itab = (int*)&lds[256];
    if (ln15 == 0) {
#pragma unroll
        for (int i = 0; i < 4; ++i)
#pragma unroll
            for (int r = 0; r < 4; ++r) {
                const int row = wm * 64 + i * 16 + quad * 4 + r;
                vtab[row * 2 + wn] = bval[i * 4 + r];
                itab[row * 2 + wn] = bidx[i * 4 + r];
            }
    }
    __syncthreads();
    if (tid < 128) {
        float v0 = vtab[tid * 2]; int i0 = itab[tid * 2];
        const float v1 = vtab[tid * 2 + 1]; const int i1 = itab[tid * 2 + 1];
        if (v1 < v0 || (v1 == v0 && i1 < i0)) { v0 = v1; i0 = i1; }
        const unsigned b   = __float_as_uint(v0);
        const unsigned key = (b & 0x80000000u) ? ~b : (b | 0x80000000u);
        const unsigned long long pk =
            ((unsigned long long)key << 32) | (unsigned long long)(unsigned)i0;
        atomicMin(&ws64[tbase + tid], pk);
    }
}

__global__ __launch_bounds__(256)
void unpack_kernel(const unsigned long long* __restrict__ w, int* __restrict__ out) {
    const int i = blockIdx.x * 256 + threadIdx.x;
    out[i] = (int)(unsigned)(w[i] & 0xFFFFFFFFull);
}

extern "C" void kernel_launch(void* const* d_in, const int* in_sizes, int n_in,
                              void* d_out, int out_size, void* d_ws, size_t ws_size,
                              hipStream_t stream) {
    const float* embed   = (const float*)d_in[0];   // [32768][768] fp32
    const float* centers = (const float*)d_in[1];   // [2048][768] fp32
    int* out = (int*)d_out;                         // [32768] int32

    if (ws_size >= WS_NEED) {
        uint4* Ap = (uint4*)((char*)d_ws + WS_APACK);
        uint4* Bp = (uint4*)((char*)d_ws + WS_BPACK);
        float* csq   = (float*)((char*)d_ws + WS_CSQ);
        uint2* slots = (uint2*)((char*)d_ws + WS_SLOT);
        fragpack_kernel<<<(NA_UNITS + NB_UNITS + NN) / 4, 256, 0, stream>>>(
            embed, centers, Ap, Bp, csq);
        gemm_pack_kernel<<<(MM / BM) * (NN / BN), 256, 0, stream>>>(
            Ap, Bp, csq, slots);
        slot_reduce_kernel<<<MM / 256, 256, 0, stream>>>(slots, out);
    } else {
        unsigned long long* ws64 = (unsigned long long*)d_ws;
        float* csq = (float*)((char*)d_ws + (size_t)MM * 8);
        init_ws_kernel<<<MM / 256, 256, 0, stream>>>(ws64);
        csq_kernel<<<NN, 64, 0, stream>>>(centers, csq);
        argmin_mfma_kernel<<<dim3(MM / BM, NN / BN), 256, 0, stream>>>(
            embed, centers, csq, ws64);
        unpack_kernel<<<MM / 256, 256, 0, stream>>>(ws64, out);
    }
}

// Round 3
// 428.954 us; speedup vs baseline: 1.0334x; 1.0286x over previous
//
#include <hip/hip_runtime.h>

// argmin_c ||x-c|| == argmin_c (||c||^2 - 2 x.c). Cross-term via 3 f16 MFMA
// GEMMs (exact hi/lo split of fp32, lo*lo dropped ~2^-22 rel).
// Round 10: LDS-staged barrier-pinned pipeline (m201-style template).
// Rounds 7-9 proved the compiler collapses any register-direct prefetch
// (VGPR stayed ~108 across i-outer/j-outer reshapes; MfmaUtil pinned at 52%).
// New gemm: 256x256 tile, BK=32, 512 thr (8 waves 2Mx4N, wave tile 128x64),
// double-buffered 128KB LDS. Staging via global_load_lds width=16 into the
// fragment-ordered pack layout (linear LDS write == fragment layout, so
// ds_read_b128 at lane*16 is conflict-free, no swizzle). Counted vmcnt(8)
// + raw s_barrier (never __syncthreads -> no forced vmcnt(0) drain) +
// sched_barrier fences pin the schedule; setprio(1) around MFMA clusters.
// Staging shared by all 8 waves kills the 2x redundant fetch of the old
// register-direct design. Accumulation order per acc element unchanged
// (kt ascending; hh,hl,lh) -> bit-identical scores -> identical argmin.
typedef __fp16 f16x2 __attribute__((ext_vector_type(2)));
typedef __fp16 f16x8 __attribute__((ext_vector_type(8)));
typedef float f32x4 __attribute__((ext_vector_type(4)));

constexpr int MM = 32768;   // B*T tokens
constexpr int NN = 2048;    // clusters
constexpr int KK = 768;     // dim
constexpr int NKT = KK / 32;          // 24 k-tiles
constexpr int NA_UNITS = (MM / 16) * NKT;   // 49152 A (mt,kt) wave-tasks
constexpr int NB_UNITS = (NN / 16) * NKT;   //  3072 B (nt,kt) wave-tasks

// Workspace layout (bytes). Apack: [mt][kt][part] 1KB units; Bpack same.
constexpr size_t WS_APACK = 0;
constexpr size_t WS_BPACK = WS_APACK + (size_t)MM * KK * 4;  // 100663296
constexpr size_t WS_CSQ   = WS_BPACK + (size_t)NN * KK * 4;  // 106954752
constexpr size_t WS_SLOT  = WS_CSQ + (size_t)NN * 4;         // 106962944
constexpr size_t WS_NEED  = WS_SLOT + (size_t)MM * 8 * 8;    // 109060096

__device__ __forceinline__ unsigned bc(f16x2 h) {
    return __builtin_bit_cast(unsigned, h);
}

// ---------------- fast path ----------------

// One wave packs one (tile16, ktile32, {hi,lo}) pair: reads 16 rows x 128B of
// fp32, writes two contiguous 1KB units in fragment order
// (byte off = (quad*16 + ln15)*16 holds elements m=ln15, k=quad*8..+7).
// Tail tasks (task >= NA+NB) compute csq: one wave per cluster row.
__global__ __launch_bounds__(256)
void fragpack_kernel(const float* __restrict__ A, const float* __restrict__ Bc,
                     uint4* __restrict__ Ap, uint4* __restrict__ Bp,
                     float* __restrict__ csq) {
    const int task = blockIdx.x * 4 + (threadIdx.x >> 6);
    const int lane = threadIdx.x & 63;

    if (task >= NA_UNITS + NB_UNITS) {          // csq tail: wave-uniform branch
        const int cl = task - (NA_UNITS + NB_UNITS);
        const float4* row = reinterpret_cast<const float4*>(Bc + (size_t)cl * KK);
        float s = 0.f;
#pragma unroll
        for (int w = 0; w < KK / (4 * 64); ++w) {
            float4 v = row[w * 64 + lane];
            s = fmaf(v.x, v.x, s); s = fmaf(v.y, v.y, s);
            s = fmaf(v.z, v.z, s); s = fmaf(v.w, v.w, s);
        }
#pragma unroll
        for (int off = 32; off > 0; off >>= 1) s += __shfl_xor(s, off, 64);
        if (lane == 0) csq[cl] = s;
        return;
    }

    const int ln15 = lane & 15;
    const int quad = lane >> 4;

    const bool isB = task >= NA_UNITS;
    const int t = isB ? task - NA_UNITS : task;
    const int tile = t / NKT, kt = t % NKT;
    const float* src = (isB ? Bc : A) + (size_t)(tile * 16 + ln15) * KK + kt * 32 + quad * 8;
    uint4* dst = (isB ? Bp : Ap) + (size_t)t * 128 + lane;   // 2 units = 128 uint4

    const float4 v0 = *(const float4*)(src);
    const float4 v1 = *(const float4*)(src + 4);
    f16x2 h0 = __builtin_amdgcn_cvt_pkrtz(v0.x, v0.y);
    f16x2 h1 = __builtin_amdgcn_cvt_pkrtz(v0.z, v0.w);
    f16x2 h2 = __builtin_amdgcn_cvt_pkrtz(v1.x, v1.y);
    f16x2 h3 = __builtin_amdgcn_cvt_pkrtz(v1.z, v1.w);
    f16x2 l0 = __builtin_amdgcn_cvt_pkrtz(v0.x-(float)h0[0], v0.y-(float)h0[1]);
    f16x2 l1 = __builtin_amdgcn_cvt_pkrtz(v0.z-(float)h1[0], v0.w-(float)h1[1]);
    f16x2 l2 = __builtin_amdgcn_cvt_pkrtz(v1.x-(float)h2[0], v1.y-(float)h2[1]);
    f16x2 l3 = __builtin_amdgcn_cvt_pkrtz(v1.z-(float)h3[0], v1.w-(float)h3[1]);
    uint4 hv = {bc(h0), bc(h1), bc(h2), bc(h3)};
    uint4 lv = {bc(l0), bc(l1), bc(l2), bc(l3)};
    dst[0]  = hv;
    dst[64] = lv;
}

__global__ __launch_bounds__(64)
void csq_kernel(const float* __restrict__ cc, float* __restrict__ csq) {
    const int cl = blockIdx.x;
    const int lane = threadIdx.x;
    const float4* row = reinterpret_cast<const float4*>(cc + (size_t)cl * KK);
    float s = 0.f;
#pragma unroll
    for (int w = 0; w < KK / (4 * 64); ++w) {
        float4 v = row[w * 64 + lane];
        s = fmaf(v.x, v.x, s); s = fmaf(v.y, v.y, s);
        s = fmaf(v.z, v.z, s); s = fmaf(v.w, v.w, s);
    }
#pragma unroll
    for (int off = 32; off > 0; off >>= 1) s += __shfl_xor(s, off, 64);
    if (lane == 0) csq[cl] = s;
}

#define MF2(a, b, c) __builtin_amdgcn_mfma_f32_16x16x32_f16(a, b, c, 0, 0, 0)

// gemm: 256x256 tile per 512-thread block. LDS double buffer, each buf:
//   A units [mtile 0..15][part hi/lo] at uint4 idx (mtile*2+part)*64
//   B units at 2048 + (ntile*2+part)*64.  Buf1 at +4096 uint4.
__global__ __launch_bounds__(512, 2)
void gemm_pack_kernel(const uint4* __restrict__ Ap, const uint4* __restrict__ Bp,
                      const float* __restrict__ csq, uint2* __restrict__ slots) {
    __shared__ uint4 ldsq[8192];   // 128 KiB

    // XCD-aware chunked swizzle: xcd = b&7; within an XCD the 8 gx-blocks of
    // a gy-panel are consecutive -> co-resident 32 blocks = 4 A-panels
    // (4 x 786KB = 3.1MB, L2-fits) x all 8 gx.
    const int b   = blockIdx.x;           // 0..1023
    const int xcd = b & 7;
    const int s   = b >> 3;               // 0..127
    const int gy  = xcd * 16 + (s >> 3);  // 0..127 m-block
    const int gx  = s & 7;                // 0..7   n-block

    const int tid  = threadIdx.x;
    const int lane = tid & 63;
    const int ln15 = lane & 15;
    const int quad = lane >> 4;
    const int wave = tid >> 6;            // 0..7
    const int wm   = wave >> 2;           // 0..1
    const int wn   = wave & 3;            // 0..3
    const int tbase = gy * 256;
    const int cb    = gx * 256;

    // Per-wave staging sources: units u = wave*8 + q, q=0..7.
    // u<32 -> A unit (mtile=u>>1, part=u&1); else B unit.
    const uint4* sp[8];
#pragma unroll
    for (int q = 0; q < 8; ++q) {
        const int u = wave * 8 + q;
        const bool isA = u < 32;
        const int v = isA ? u : u - 32;
        const int tile = (isA ? gy * 16 : gx * 16) + (v >> 1);
        const int part = v & 1;
        sp[q] = (isA ? Ap : Bp) + (size_t)tile * NKT * 128 + part * 64 + lane;
    }
    const int myunit = wave * 8 * 64;     // uint4 idx of this wave's first unit

    auto STAGE = [&](int kt, int bufq) {
#pragma unroll
        for (int q = 0; q < 8; ++q) {
            __builtin_amdgcn_global_load_lds(
                (const __attribute__((address_space(1))) unsigned int*)(sp[q] + kt * 128),
                (__attribute__((address_space(3))) unsigned int*)&ldsq[bufq + myunit + q * 64],
                16, 0, 0);
        }
    };

    f32x4 acc[8][4];
#pragma unroll
    for (int i = 0; i < 8; ++i)
#pragma unroll
        for (int j = 0; j < 4; ++j) { f32x4 z = {0.f,0.f,0.f,0.f}; acc[i][j] = z; }

    STAGE(0, 0);

    auto BODY = [&](int kt, int bufq, int nxtq, bool stage_next) {
        if (stage_next) {
            STAGE(kt + 1, nxtq);
            asm volatile("s_waitcnt vmcnt(8)" ::: "memory");
        } else {
            asm volatile("s_waitcnt vmcnt(0)" ::: "memory");
        }
        __builtin_amdgcn_sched_barrier(0);
        __builtin_amdgcn_s_barrier();        // all waves' tile-kt data landed
        __builtin_amdgcn_sched_barrier(0);

        f16x8 Bh[4], Bl[4];
#pragma unroll
        for (int j = 0; j < 4; ++j) {
            const int nu = (wn * 4 + j) * 2;
            Bh[j] = *(const f16x8*)&ldsq[bufq + 2048 + nu * 64 + lane];
            Bl[j] = *(const f16x8*)&ldsq[bufq + 2048 + (nu + 1) * 64 + lane];
        }
#pragma unroll
        for (int p = 0; p < 4; ++p) {
            f16x8 Ah[2], Al[2];
#pragma unroll
            for (int t2 = 0; t2 < 2; ++t2) {
                const int au = (wm * 8 + p * 2 + t2) * 2;
                Ah[t2] = *(const f16x8*)&ldsq[bufq + au * 64 + lane];
                Al[t2] = *(const f16x8*)&ldsq[bufq + (au + 1) * 64 + lane];
            }
            __builtin_amdgcn_s_setprio(1);
#pragma unroll
            for (int t2 = 0; t2 < 2; ++t2) {
                const int i = p * 2 + t2;
#pragma unroll
                for (int j = 0; j < 4; ++j) {
                    acc[i][j] = MF2(Ah[t2], Bh[j], acc[i][j]);
                    acc[i][j] = MF2(Ah[t2], Bl[j], acc[i][j]);
                    acc[i][j] = MF2(Al[t2], Bh[j], acc[i][j]);
                }
            }
            __builtin_amdgcn_s_setprio(0);
        }
        __builtin_amdgcn_sched_barrier(0);
        __builtin_amdgcn_s_barrier();        // release buf for overwrite
        __builtin_amdgcn_sched_barrier(0);
    };

#pragma unroll 1
    for (int kt = 0; kt < NKT - 2; kt += 2) {
        BODY(kt,     0,    4096, true);
        BODY(kt + 1, 4096, 0,    true);
    }
    BODY(NKT - 2, 0,    4096, true);
    BODY(NKT - 1, 4096, 0,    false);

    // Epilogue: score = csq - 2*dot; C/D layout col=lane&15, row=quad*4+reg.
    float csq4[4];
#pragma unroll
    for (int j = 0; j < 4; ++j) csq4[j] = csq[cb + wn * 64 + j * 16 + ln15];

    float bval[32]; int bidx[32];
#pragma unroll
    for (int i = 0; i < 8; ++i)
#pragma unroll
        for (int r = 0; r < 4; ++r) {
            const int rid = i * 4 + r;
            float bv_ = csq4[0] - 2.0f * acc[i][0][r];
            int   bi_ = cb + wn * 64 + ln15;
#pragma unroll
            for (int j = 1; j < 4; ++j) {
                const float s2 = csq4[j] - 2.0f * acc[i][j][r];
                const int   c = cb + wn * 64 + j * 16 + ln15;
                if (s2 < bv_) { bv_ = s2; bi_ = c; }   // ascending c, strict <
            }
            bval[rid] = bv_; bidx[rid] = bi_;
        }
#pragma unroll
    for (int off = 1; off < 16; off <<= 1) {
#pragma unroll
        for (int rid = 0; rid < 32; ++rid) {
            const float ov = __shfl_xor(bval[rid], off, 64);
            const int   oi = __shfl_xor(bidx[rid], off, 64);
            if (ov < bval[rid] || (ov == bval[rid] && oi < bidx[rid])) {
                bval[rid] = ov; bidx[rid] = oi;
            }
        }
    }

    __syncthreads();                       // all MFMA LDS reads done; reuse LDS
    float* vtab = (float*)&ldsq[0];        // [256 rows][4 wn]
    int*   itab = (int*)&ldsq[256];
    if (ln15 == 0) {
#pragma unroll
        for (int i = 0; i < 8; ++i)
#pragma unroll
            for (int r = 0; r < 4; ++r) {
                const int row = wm * 128 + i * 16 + quad * 4 + r;
                vtab[row * 4 + wn] = bval[i * 4 + r];
                itab[row * 4 + wn] = bidx[i * 4 + r];
            }
    }
    __syncthreads();
    if (tid < 256) {
        float v0 = vtab[tid * 4]; int i0 = itab[tid * 4];
#pragma unroll
        for (int e = 1; e < 4; ++e) {
            const float v1 = vtab[tid * 4 + e]; const int i1 = itab[tid * 4 + e];
            if (v1 < v0 || (v1 == v0 && i1 < i0)) { v0 = v1; i0 = i1; }
        }
        uint2 e; e.x = __float_as_uint(v0); e.y = (unsigned)i0;
        slots[(size_t)(tbase + tid) * 8 + gx] = e;
    }
}

__global__ __launch_bounds__(256)
void slot_reduce_kernel(const uint2* __restrict__ slots, int* __restrict__ out) {
    const int t = blockIdx.x * 256 + threadIdx.x;
    const uint2* s = slots + (size_t)t * 8;
    float bv = __uint_as_float(s[0].x); int bi = (int)s[0].y;
#pragma unroll
    for (int j = 1; j < 8; ++j) {
        const uint2 e = s[j];
        const float v = __uint_as_float(e.x);
        if (v < bv || (v == bv && (int)e.y < bi)) { bv = v; bi = (int)e.y; }
    }
    out[t] = bi;
}

// ---------------- round-3 fallback (proven, used only if ws too small) ------

__global__ __launch_bounds__(256)
void init_ws_kernel(unsigned long long* __restrict__ w) {
    w[blockIdx.x * 256 + threadIdx.x] = 0xFFFFFFFFFFFFFFFFull;
}

__global__ __launch_bounds__(256, 2)
void argmin_mfma_kernel(const float* __restrict__ A, const float* __restrict__ Bc,
                        const float* __restrict__ csq,
                        unsigned long long* __restrict__ ws64) {
    __shared__ unsigned lds[4 * 128 * 20];
    constexpr int AH = 0, AL = 2560, BH = 5120;

    const int tid  = threadIdx.x;
    const int lane = tid & 63;
    const int ln15 = lane & 15;
    const int quad = lane >> 4;
    const int wave = tid >> 6;
    const int wm = wave >> 1, wn = wave & 1;
    const int tbase = blockIdx.x * 128;
    const int cb    = blockIdx.y * 128;

    const int sr  = tid >> 1;
    const int skh = tid & 1;
    const float* gA = A  + (size_t)(tbase + sr) * KK + skh * 16;
    const float* gB = Bc + (size_t)(cb   + sr) * KK + skh * 16;
    const int wword = sr * 20 + skh * 8;

    f32x4 acc[4][4];
#pragma unroll
    for (int i = 0; i < 4; ++i)
#pragma unroll
        for (int j = 0; j < 4; ++j) { f32x4 z = {0.f,0.f,0.f,0.f}; acc[i][j] = z; }

    float4 av[4], bv[4];
#pragma unroll
    for (int p = 0; p < 4; ++p) {
        av[p] = *(const float4*)(gA + p * 4);
        bv[p] = *(const float4*)(gB + p * 4);
    }

    int aw[4], bw[4];
#pragma unroll
    for (int i = 0; i < 4; ++i) {
        aw[i] = AH + (wm * 64 + i * 16 + ln15) * 20 + quad * 4;
        bw[i] = BH + (wn * 64 + i * 16 + ln15) * 20 + quad * 4;
    }

    for (int k0 = 0; k0 < KK; k0 += 32) {
        __syncthreads();
#pragma unroll
        for (int h = 0; h < 2; ++h) {
            float4 v0 = av[2*h], v1 = av[2*h+1];
            f16x2 h00 = __builtin_amdgcn_cvt_pkrtz(v0.x, v0.y);
            f16x2 h01 = __builtin_amdgcn_cvt_pkrtz(v0.z, v0.w);
            f16x2 h10 = __builtin_amdgcn_cvt_pkrtz(v1.x, v1.y);
            f16x2 h11 = __builtin_amdgcn_cvt_pkrtz(v1.z, v1.w);
            f16x2 l00 = __builtin_amdgcn_cvt_pkrtz(v0.x-(float)h00[0], v0.y-(float)h00[1]);
            f16x2 l01 = __builtin_amdgcn_cvt_pkrtz(v0.z-(float)h01[0], v0.w-(float)h01[1]);
            f16x2 l10 = __builtin_amdgcn_cvt_pkrtz(v1.x-(float)h10[0], v1.y-(float)h10[1]);
            f16x2 l11 = __builtin_amdgcn_cvt_pkrtz(v1.z-(float)h11[0], v1.w-(float)h11[1]);
            uint4 hv = {bc(h00), bc(h01), bc(h10), bc(h11)};
            uint4 lv = {bc(l00), bc(l01), bc(l10), bc(l11)};
            *(uint4*)&lds[AH + wword + 4*h] = hv;
            *(uint4*)&lds[AL + wword + 4*h] = lv;

            float4 w0 = bv[2*h], w1 = bv[2*h+1];
            f16x2 g00 = __builtin_amdgcn_cvt_pkrtz(w0.x, w0.y);
            f16x2 g01 = __builtin_amdgcn_cvt_pkrtz(w0.z, w0.w);
            f16x2 g10 = __builtin_amdgcn_cvt_pkrtz(w1.x, w1.y);
            f16x2 g11 = __builtin_amdgcn_cvt_pkrtz(w1.z, w1.w);
            f16x2 m00 = __builtin_amdgcn_cvt_pkrtz(w0.x-(float)g00[0], w0.y-(float)g00[1]);
            f16x2 m01 = __builtin_amdgcn_cvt_pkrtz(w0.z-(float)g01[0], w0.w-(float)g01[1]);
            f16x2 m10 = __builtin_amdgcn_cvt_pkrtz(w1.x-(float)g10[0], w1.y-(float)g10[1]);
            f16x2 m11 = __builtin_amdgcn_cvt_pkrtz(w1.z-(float)g11[0], w1.w-(float)g11[1]);
            uint4 gv = {bc(g00), bc(g01), bc(g10), bc(g11)};
            uint4 mv = {bc(m00), bc(m01), bc(m10), bc(m11)};
            *(uint4*)&lds[BH + wword + 4*h]        = gv;
            *(uint4*)&lds[BH + 2560 + wword + 4*h] = mv;
        }
        __syncthreads();

        const int kn = k0 + 32;
        if (kn < KK) {
#pragma unroll
            for (int p = 0; p < 4; ++p) {
                av[p] = *(const float4*)(gA + kn + p * 4);
                bv[p] = *(const float4*)(gB + kn + p * 4);
            }
        }

        f16x8 a_h[4], a_l[4], b_h[4], b_l[4];
#pragma unroll
        for (int i = 0; i < 4; ++i) {
            a_h[i] = *(const f16x8*)&lds[aw[i]];
            a_l[i] = *(const f16x8*)&lds[aw[i] + 2560];
            b_h[i] = *(const f16x8*)&lds[bw[i]];
            b_l[i] = *(const f16x8*)&lds[bw[i] + 2560];
        }
#pragma unroll
        for (int i = 0; i < 4; ++i)
#pragma unroll
            for (int j = 0; j < 4; ++j) {
                acc[i][j] = __builtin_amdgcn_mfma_f32_16x16x32_f16(a_h[i], b_h[j], acc[i][j], 0, 0, 0);
                acc[i][j] = __builtin_amdgcn_mfma_f32_16x16x32_f16(a_h[i], b_l[j], acc[i][j], 0, 0, 0);
                acc[i][j] = __builtin_amdgcn_mfma_f32_16x16x32_f16(a_l[i], b_h[j], acc[i][j], 0, 0, 0);
            }
    }

    float csq4[4];
#pragma unroll
    for (int j = 0; j < 4; ++j) csq4[j] = csq[cb + wn * 64 + j * 16 + ln15];

    float bval[16]; int bidx[16];
#pragma unroll
    for (int i = 0; i < 4; ++i)
#pragma unroll
        for (int r = 0; r < 4; ++r) {
            const int rid = i * 4 + r;
            float bv_ = csq4[0] - 2.0f * acc[i][0][r];
            int   bi_ = cb + wn * 64 + ln15;
#pragma unroll
            for (int j = 1; j < 4; ++j) {
                const float s = csq4[j] - 2.0f * acc[i][j][r];
                const int   c = cb + wn * 64 + j * 16 + ln15;
                if (s < bv_) { bv_ = s; bi_ = c; }
            }
            bval[rid] = bv_; bidx[rid] = bi_;
        }
#pragma unroll
    for (int off = 1; off < 16; off <<= 1) {
#pragma unroll
        for (int rid = 0; rid < 16; ++rid) {
            const float ov = __shfl_xor(bval[rid], off, 64);
            const int   oi = __shfl_xor(bidx[rid], off, 64);
            if (ov < bval[rid] || (ov == bval[rid] && oi < bidx[rid])) {
                bval[rid] = ov; bidx[rid] = oi;
            }
        }
    }

    __syncthreads();
    float* vtab = (float*)&lds[0];
    int*   itab = (int*)&lds[256];
    if (ln15 == 0) {
#pragma unroll
        for (int i = 0; i < 4; ++i)
#pragma unroll
            for (int r = 0; r < 4; ++r) {
                const int row = wm * 64 + i * 16 + quad * 4 + r;
                vtab[row * 2 + wn] = bval[i * 4 + r];
                itab[row * 2 + wn] = bidx[i * 4 + r];
            }
    }
    __syncthreads();
    if (tid < 128) {
        float v0 = vtab[tid * 2]; int i0 = itab[tid * 2];
        const float v1 = vtab[tid * 2 + 1]; const int i1 = itab[tid * 2 + 1];
        if (v1 < v0 || (v1 == v0 && i1 < i0)) { v0 = v1; i0 = i1; }
        const unsigned b   = __float_as_uint(v0);
        const unsigned key = (b & 0x80000000u) ? ~b : (b | 0x80000000u);
        const unsigned long long pk =
            ((unsigned long long)key << 32) | (unsigned long long)(unsigned)i0;
        atomicMin(&ws64[tbase + tid], pk);
    }
}

__global__ __launch_bounds__(256)
void unpack_kernel(const unsigned long long* __restrict__ w, int* __restrict__ out) {
    const int i = blockIdx.x * 256 + threadIdx.x;
    out[i] = (int)(unsigned)(w[i] & 0xFFFFFFFFull);
}

extern "C" void kernel_launch(void* const* d_in, const int* in_sizes, int n_in,
                              void* d_out, int out_size, void* d_ws, size_t ws_size,
                              hipStream_t stream) {
    const float* embed   = (const float*)d_in[0];   // [32768][768] fp32
    const float* centers = (const float*)d_in[1];   // [2048][768] fp32
    int* out = (int*)d_out;                         // [32768] int32

    if (ws_size >= WS_NEED) {
        uint4* Ap = (uint4*)((char*)d_ws + WS_APACK);
        uint4* Bp = (uint4*)((char*)d_ws + WS_BPACK);
        float* csq   = (float*)((char*)d_ws + WS_CSQ);
        uint2* slots = (uint2*)((char*)d_ws + WS_SLOT);
        fragpack_kernel<<<(NA_UNITS + NB_UNITS + NN) / 4, 256, 0, stream>>>(
            embed, centers, Ap, Bp, csq);
        gemm_pack_kernel<<<(MM / 256) * (NN / 256), 512, 0, stream>>>(
            Ap, Bp, csq, slots);
        slot_reduce_kernel<<<MM / 256, 256, 0, stream>>>(slots, out);
    } else {
        unsigned long long* ws64 = (unsigned long long*)d_ws;
        float* csq = (float*)((char*)d_ws + (size_t)MM * 8);
        init_ws_kernel<<<MM / 256, 256, 0, stream>>>(ws64);
        csq_kernel<<<NN, 64, 0, stream>>>(centers, csq);
        argmin_mfma_kernel<<<dim3(MM / 128, NN / 128), 256, 0, stream>>>(
            embed, centers, csq, ws64);
        unpack_kernel<<<MM / 256, 256, 0, stream>>>(ws64, out);
    }
}